// Round 5
// baseline (178.862 us; speedup 1.0000x reference)
//
#include <hip/hip_runtime.h>
#include <hip/hip_cooperative_groups.h>

namespace cg = cooperative_groups;

// Bahdanau multi-head attention, fp32 in/out, B=2 L=128 D=512 H=8 dh=64.
// R5: ONE cooperative kernel (256 blocks x 512 thr) with the R4 phase bodies:
//     MFMA fp16 GEMMs (8-wave 64x64 tiles) + fp32 trans-pipe attn core.
//     3 grid syncs replace 3 kernel-launch boundaries (~10 us each).

#define NHEADS 8
#define DH 64
#define DM 512
#define BB 2
#define LQL 128
#define LKL 128
#define QPB 8

typedef _Float16 v8h __attribute__((ext_vector_type(8)));
typedef _Float16 v4h __attribute__((ext_vector_type(4)));
typedef float v4f __attribute__((ext_vector_type(4)));

static __device__ __forceinline__ float fexp2(float x) { return __builtin_amdgcn_exp2f(x); }
static __device__ __forceinline__ float frcp(float x)  { return __builtin_amdgcn_rcpf(x); }

static __device__ __forceinline__ v4h cvt4(const float4 a) {
    v4h h;
    h[0] = (_Float16)a.x; h[1] = (_Float16)a.y;
    h[2] = (_Float16)a.z; h[3] = (_Float16)a.w;
    return h;
}

struct P {
    const float *xq, *xk, *xv, *Wq, *Wk, *Wv, *Wo, *Wqa, *Wka, *wv;
    const int* vl;
    _Float16 *Qh, *Kh, *interh;
    float *V, *qf, *kf, *out;
};

union SMem {
    struct { _Float16 As[64][40]; _Float16 Ws[64][40]; } g;   // 10.2 KB
    struct { float qf2[QPB][DM]; float wv2[DM];
             float part[4][QPB][LKL]; float attn[QPB][LKL]; } c;  // 38.9 KB
};

// ---- Phase A: Q/K/V = X @ W^T. 96 jobs of 64x64, K=512. 8 waves/block. ----
static __device__ void phaseA(const P& p, SMem& sm, int bid0, int nb) {
    const int tid = threadIdx.x, w = tid >> 6, lane = tid & 63;
    const int srow = tid >> 3, sseg = tid & 7;        // stage: 64 rows x 8 segs
    const int fr = lane & 15, fg = (lane >> 4) * 8;
    const int mstrip = w & 3, nh = (w >> 2) * 2;      // wave: m-strip + 2 n-subtiles
    for (int j = bid0; j < 96; j += nb) {
        const int mat = j >> 5, tj = j & 31;
        const int bn0 = (tj & 7) * 64, bm0 = (tj >> 3) * 64;
        if (mat && (bm0 & 127) >= p.vl[bm0 >> 7]) continue;  // masked K/V tiles
        const float* A = mat == 0 ? p.xq : (mat == 1 ? p.xk : p.xv);
        const float* W = mat == 0 ? p.Wq : (mat == 1 ? p.Wk : p.Wv);
        v4f acc0 = {}, acc1 = {};
        for (int k0 = 0; k0 < DM; k0 += 32) {
            const float4 a4 = *(const float4*)(A + (size_t)(bm0 + srow) * DM + k0 + sseg * 4);
            const float4 w4 = *(const float4*)(W + (size_t)(bn0 + srow) * DM + k0 + sseg * 4);
            __syncthreads();
            *(v4h*)&sm.g.As[srow][sseg * 4] = cvt4(a4);
            *(v4h*)&sm.g.Ws[srow][sseg * 4] = cvt4(w4);
            __syncthreads();
            const v8h af = *(const v8h*)&sm.g.As[mstrip * 16 + fr][fg];
            const v8h b0 = *(const v8h*)&sm.g.Ws[nh * 16 + fr][fg];
            const v8h b1 = *(const v8h*)&sm.g.Ws[(nh + 1) * 16 + fr][fg];
            acc0 = __builtin_amdgcn_mfma_f32_16x16x32_f16(af, b0, acc0, 0, 0, 0);
            acc1 = __builtin_amdgcn_mfma_f32_16x16x32_f16(af, b1, acc1, 0, 0, 0);
        }
        #pragma unroll
        for (int rg = 0; rg < 4; ++rg) {
            const int row = bm0 + mstrip * 16 + (lane >> 4) * 4 + rg;
            const int c0 = bn0 + nh * 16 + fr, c1 = c0 + 16;
            if (mat == 0) {
                p.Qh[(size_t)row * DM + c0] = (_Float16)acc0[rg];
                p.Qh[(size_t)row * DM + c1] = (_Float16)acc1[rg];
            } else if (mat == 1) {
                p.Kh[(size_t)row * DM + c0] = (_Float16)acc0[rg];
                p.Kh[(size_t)row * DM + c1] = (_Float16)acc1[rg];
            } else {
                p.V[(size_t)row * DM + c0] = acc0[rg];
                p.V[(size_t)row * DM + c1] = acc1[rg];
            }
        }
    }
}

// ---- Phase B: qf/kf = head-gathered Q/K @ Wa^T. 512 jobs of 64x64, K=64. --
static __device__ void phaseB(const P& p, SMem& sm, int bid0, int nb) {
    const int tid = threadIdx.x, w = tid >> 6, lane = tid & 63;
    const int srow = tid >> 3, sseg = tid & 7;
    const int fr = lane & 15, fg = (lane >> 4) * 8;
    const int mstrip = w & 3, nh = (w >> 2) * 2;
    for (int j = bid0; j < 512; j += nb) {
        const int mat = j >> 8, tj = j & 255;
        const int bn0 = (tj & 7) * 64, bm0 = (tj >> 3) * 64;
        if (mat && (bm0 & 127) >= p.vl[bm0 >> 10]) continue;  // masked kf tiles
        const _Float16* Asrc = mat ? p.Kh : p.Qh;
        const float* W = mat ? p.Wka : p.Wqa;
        float* C = mat ? p.kf : p.qf;
        const int r = bm0 + srow;
        const int b = r >> 10, h = (r >> 7) & 7, l = r & 127;
        const _Float16* arow = Asrc + (size_t)(b * LQL + l) * DM + h * DH;
        v4f acc0 = {}, acc1 = {};
        #pragma unroll
        for (int k0 = 0; k0 < DH; k0 += 32) {
            const v4h ha = *(const v4h*)(arow + k0 + sseg * 4);
            const float4 w4 = *(const float4*)(W + (size_t)(bn0 + srow) * DH + k0 + sseg * 4);
            __syncthreads();
            *(v4h*)&sm.g.As[srow][sseg * 4] = ha;
            *(v4h*)&sm.g.Ws[srow][sseg * 4] = cvt4(w4);
            __syncthreads();
            const v8h af = *(const v8h*)&sm.g.As[mstrip * 16 + fr][fg];
            const v8h b0 = *(const v8h*)&sm.g.Ws[nh * 16 + fr][fg];
            const v8h b1 = *(const v8h*)&sm.g.Ws[(nh + 1) * 16 + fr][fg];
            acc0 = __builtin_amdgcn_mfma_f32_16x16x32_f16(af, b0, acc0, 0, 0, 0);
            acc1 = __builtin_amdgcn_mfma_f32_16x16x32_f16(af, b1, acc1, 0, 0, 0);
        }
        #pragma unroll
        for (int rg = 0; rg < 4; ++rg) {
            const int row = bm0 + mstrip * 16 + (lane >> 4) * 4 + rg;
            const int c0 = bn0 + nh * 16 + fr;
            C[(size_t)row * DM + c0]      = acc0[rg];
            C[(size_t)row * DM + c0 + 16] = acc1[rg];
        }
    }
}

// ---- Phase C: fused score + masked softmax + PV (fp32). 256 jobs. ---------
static __device__ void phaseC(const P& p, SMem& sm, int bid0, int nb) {
    const float C2 = 2.8853900818f;        // 2*log2(e)
    const float LOG2E = 1.4426950409f;
    const int t = threadIdx.x;
    for (int j = bid0; j < 256; j += nb) {
        const int b  = j >> 7;
        const int h  = (j >> 4) & 7;
        const int qt = j & 15;
        const int qbase = qt * QPB;
        const int bh = b * NHEADS + h;
        const int Lv = p.vl[b];
        __syncthreads();                   // protect LDS reuse across jobs

        {   // stage qf (pre-scaled by 2log2e) and wv (pre-scaled by -2)
            const int r = t >> 6, cc = (t & 63) * 8;
            const float4* q4 = (const float4*)(p.qf + ((size_t)(bh * LQL + qbase + r)) * DM + cc);
            const float4 v0 = q4[0], v1 = q4[1];
            sm.c.qf2[r][cc+0] = v0.x * C2; sm.c.qf2[r][cc+1] = v0.y * C2;
            sm.c.qf2[r][cc+2] = v0.z * C2; sm.c.qf2[r][cc+3] = v0.w * C2;
            sm.c.qf2[r][cc+4] = v1.x * C2; sm.c.qf2[r][cc+5] = v1.y * C2;
            sm.c.qf2[r][cc+6] = v1.z * C2; sm.c.qf2[r][cc+7] = v1.w * C2;
            sm.c.wv2[t] = p.wv[t] * -2.0f;
        }
        __syncthreads();

        const int k = t & 127, fq = t >> 7;
        float acc[QPB] = {};
        if (k < Lv) {                      // whole-wave skip of masked k ranges
            const float* kp = p.kf + ((size_t)(bh * LKL + k)) * DM + fq * 128;
            float4 kA = *(const float4*)kp;
            float4 kB = *(const float4*)(kp + 4);
            #pragma unroll 1
            for (int it = 0; it < 16; ++it) {
                float4 nA, nB;
                if (it < 15) { nA = *(const float4*)(kp + 8); nB = *(const float4*)(kp + 12); }
                else         { nA = kA; nB = kB; }
                const int f0 = fq * 128 + it * 8;
                const float4 w0 = *(const float4*)&sm.c.wv2[f0];
                const float4 w1 = *(const float4*)&sm.c.wv2[f0 + 4];
                #pragma unroll
                for (int q = 0; q < QPB; ++q) {
                    const float4 q0 = *(const float4*)&sm.c.qf2[q][f0];
                    const float4 q1 = *(const float4*)&sm.c.qf2[q][f0 + 4];
                    float a = acc[q];
                    a = fmaf(w0.x, frcp(fexp2(fmaf(kA.x, C2, q0.x)) + 1.f), a);
                    a = fmaf(w0.y, frcp(fexp2(fmaf(kA.y, C2, q0.y)) + 1.f), a);
                    a = fmaf(w0.z, frcp(fexp2(fmaf(kA.z, C2, q0.z)) + 1.f), a);
                    a = fmaf(w0.w, frcp(fexp2(fmaf(kA.w, C2, q0.w)) + 1.f), a);
                    a = fmaf(w1.x, frcp(fexp2(fmaf(kB.x, C2, q1.x)) + 1.f), a);
                    a = fmaf(w1.y, frcp(fexp2(fmaf(kB.y, C2, q1.y)) + 1.f), a);
                    a = fmaf(w1.z, frcp(fexp2(fmaf(kB.z, C2, q1.z)) + 1.f), a);
                    a = fmaf(w1.w, frcp(fexp2(fmaf(kB.w, C2, q1.w)) + 1.f), a);
                    acc[q] = a;
                }
                kA = nA; kB = nB; kp += 8;
            }
        }
        #pragma unroll
        for (int q = 0; q < QPB; ++q) sm.c.part[fq][q][k] = acc[q];
        __syncthreads();

        {   // masked softmax: wave w = q-row w; lane covers k=lane, k=lane+64
            const int q = t >> 6, lane = t & 63;
            float v0 = -3.0e38f, v1 = -3.0e38f;
            if (lane < Lv)
                v0 = sm.c.part[0][q][lane] + sm.c.part[1][q][lane]
                   + sm.c.part[2][q][lane] + sm.c.part[3][q][lane];
            if (lane + 64 < Lv)
                v1 = sm.c.part[0][q][lane+64] + sm.c.part[1][q][lane+64]
                   + sm.c.part[2][q][lane+64] + sm.c.part[3][q][lane+64];
            float m = fmaxf(v0, v1);
            #pragma unroll
            for (int off = 32; off; off >>= 1) m = fmaxf(m, __shfl_xor(m, off, 64));
            const float e0 = fexp2((v0 - m) * LOG2E);
            const float e1 = fexp2((v1 - m) * LOG2E);
            float s = e0 + e1;
            #pragma unroll
            for (int off = 32; off; off >>= 1) s += __shfl_xor(s, off, 64);
            const float inv = frcp(s);
            sm.c.attn[q][lane]      = e0 * inv;
            sm.c.attn[q][lane + 64] = e1 * inv;
        }
        __syncthreads();

        {   // PV: thread (q = t>>6 & 7 via two halves, d = t&63); fp16 store
            const int q = t >> 6, d = t & 63;
            const float* vb = p.V + ((size_t)(b * LKL)) * DM + h * DH + d;
            float a0 = 0.f, a1 = 0.f, a2 = 0.f, a3 = 0.f;
            int kk = 0;
            for (; kk + 4 <= Lv; kk += 4) {
                a0 += sm.c.attn[q][kk+0] * vb[(size_t)(kk+0) * DM];
                a1 += sm.c.attn[q][kk+1] * vb[(size_t)(kk+1) * DM];
                a2 += sm.c.attn[q][kk+2] * vb[(size_t)(kk+2) * DM];
                a3 += sm.c.attn[q][kk+3] * vb[(size_t)(kk+3) * DM];
            }
            for (; kk < Lv; ++kk) a0 += sm.c.attn[q][kk] * vb[(size_t)kk * DM];
            p.interh[((size_t)(b * LQL + qbase + q)) * DM + h * DH + d] =
                (_Float16)((a0 + a1) + (a2 + a3));
        }
    }
}

// ---- Phase D: out = inter @ Wo^T. 32 jobs of 64x64, K=512. -----------------
static __device__ void phaseD(const P& p, SMem& sm, int bid0, int nb) {
    const int tid = threadIdx.x, w = tid >> 6, lane = tid & 63;
    const int srow = tid >> 3, sseg = tid & 7;
    const int fr = lane & 15, fg = (lane >> 4) * 8;
    const int mstrip = w & 3, nh = (w >> 2) * 2;
    for (int j = bid0; j < 32; j += nb) {
        const int bn0 = (j & 7) * 64, bm0 = (j >> 3) * 64;
        v4f acc0 = {}, acc1 = {};
        for (int k0 = 0; k0 < DM; k0 += 32) {
            const v4h ha = *(const v4h*)(p.interh + (size_t)(bm0 + srow) * DM + k0 + sseg * 4);
            const float4 w4 = *(const float4*)(p.Wo + (size_t)(bn0 + srow) * DM + k0 + sseg * 4);
            __syncthreads();
            *(v4h*)&sm.g.As[srow][sseg * 4] = ha;
            *(v4h*)&sm.g.Ws[srow][sseg * 4] = cvt4(w4);
            __syncthreads();
            const v8h af = *(const v8h*)&sm.g.As[mstrip * 16 + fr][fg];
            const v8h b0 = *(const v8h*)&sm.g.Ws[nh * 16 + fr][fg];
            const v8h b1 = *(const v8h*)&sm.g.Ws[(nh + 1) * 16 + fr][fg];
            acc0 = __builtin_amdgcn_mfma_f32_16x16x32_f16(af, b0, acc0, 0, 0, 0);
            acc1 = __builtin_amdgcn_mfma_f32_16x16x32_f16(af, b1, acc1, 0, 0, 0);
        }
        #pragma unroll
        for (int rg = 0; rg < 4; ++rg) {
            const int row = bm0 + mstrip * 16 + (lane >> 4) * 4 + rg;
            const int c0 = bn0 + nh * 16 + fr;
            p.out[(size_t)row * DM + c0]      = acc0[rg];
            p.out[(size_t)row * DM + c0 + 16] = acc1[rg];
        }
    }
}

__global__ __launch_bounds__(512, 1) void fused_kernel(P p) {
    __shared__ SMem sm;
    cg::grid_group g = cg::this_grid();
    phaseA(p, sm, blockIdx.x, gridDim.x);
    g.sync();
    phaseB(p, sm, blockIdx.x, gridDim.x);
    g.sync();
    phaseC(p, sm, blockIdx.x, gridDim.x);
    g.sync();
    phaseD(p, sm, blockIdx.x, gridDim.x);
}

// Fallback: 4 separate launches (== R4 behavior) if coop launch unsupported.
__global__ __launch_bounds__(512) void kA(P p) { __shared__ SMem sm; phaseA(p, sm, blockIdx.x, gridDim.x); }
__global__ __launch_bounds__(512) void kB(P p) { __shared__ SMem sm; phaseB(p, sm, blockIdx.x, gridDim.x); }
__global__ __launch_bounds__(512) void kC(P p) { __shared__ SMem sm; phaseC(p, sm, blockIdx.x, gridDim.x); }
__global__ __launch_bounds__(512) void kD(P p) { __shared__ SMem sm; phaseD(p, sm, blockIdx.x, gridDim.x); }

extern "C" void kernel_launch(void* const* d_in, const int* in_sizes, int n_in,
                              void* d_out, int out_size, void* d_ws, size_t ws_size,
                              hipStream_t stream)
{
    P p;
    p.xq  = (const float*)d_in[0];
    p.xk  = (const float*)d_in[1];
    p.xv  = (const float*)d_in[2];
    p.vl  = (const int*)d_in[3];
    p.Wq  = (const float*)d_in[4];
    p.Wk  = (const float*)d_in[5];
    p.Wv  = (const float*)d_in[6];
    p.Wo  = (const float*)d_in[7];
    p.Wqa = (const float*)d_in[8];
    p.Wka = (const float*)d_in[9];
    p.wv  = (const float*)d_in[10];
    // ws carve (bytes): Qh 256K | Kh 256K | V 512K | qf 4M | kf 4M | interh 256K
    char* base = (char*)d_ws;
    p.Qh     = (_Float16*)(base);
    p.Kh     = (_Float16*)(base + 262144);
    p.V      = (float*)   (base + 524288);
    p.qf     = (float*)   (base + 1048576);
    p.kf     = (float*)   (base + 5242880);
    p.interh = (_Float16*)(base + 9437184);
    p.out    = (float*)d_out;

    void* args[] = { &p };
    hipError_t e = hipLaunchCooperativeKernel((const void*)fused_kernel,
                                              dim3(256), dim3(512), args, 0, stream);
    if (e != hipSuccess) {
        kA<<<dim3(96),  dim3(512), 0, stream>>>(p);
        kB<<<dim3(512), dim3(512), 0, stream>>>(p);
        kC<<<dim3(256), dim3(512), 0, stream>>>(p);
        kD<<<dim3(32),  dim3(512), 0, stream>>>(p);
    }
}

// Round 6
// 60.005 us; speedup vs baseline: 2.9808x; 2.9808x over previous
//
#include <hip/hip_runtime.h>

// Bahdanau multi-head attention, fp32 in/out, B=2 L=128 D=512 H=8 dh=64.
// R6: R4's proven 4-launch structure. GEMMs via fp16 MFMA (unchanged).
//     attn: 512 blocks x 512 thr (QPB=4) -> 4 waves/SIMD for latency hiding;
//     wave owns 16-k block (skip granularity 16, spread across SIMDs).

#define NHEADS 8
#define DH 64
#define DM 512
#define BB 2
#define LQL 128
#define LKL 128
#define QPB 4

typedef _Float16 v8h __attribute__((ext_vector_type(8)));
typedef float v4f __attribute__((ext_vector_type(4)));

static __device__ __forceinline__ float fexp2(float x) { return __builtin_amdgcn_exp2f(x); }
static __device__ __forceinline__ float frcp(float x)  { return __builtin_amdgcn_rcpf(x); }

static __device__ __forceinline__ v8h cvt8(const float4 a, const float4 b) {
    v8h h;
    h[0] = (_Float16)a.x; h[1] = (_Float16)a.y; h[2] = (_Float16)a.z; h[3] = (_Float16)a.w;
    h[4] = (_Float16)b.x; h[5] = (_Float16)b.y; h[6] = (_Float16)b.z; h[7] = (_Float16)b.w;
    return h;
}

// ---------------- Stage 1: Q/K/V = X @ W^T via MFMA -------------------------
__global__ __launch_bounds__(256) void qkv_mfma(
    const float* __restrict__ xq, const float* __restrict__ xk, const float* __restrict__ xv,
    const float* __restrict__ Wq, const float* __restrict__ Wk, const float* __restrict__ Wv,
    const int* __restrict__ vl,
    _Float16* __restrict__ Qh, _Float16* __restrict__ Kh, float* __restrict__ V)
{
    const int mat = blockIdx.z;
    const float* A; const float* W;
    if (mat == 0)      { A = xq; W = Wq; }
    else if (mat == 1) { A = xk; W = Wk; }
    else               { A = xv; W = Wv; }
    const int bm0 = blockIdx.y * 64, bn0 = blockIdx.x * 64;
    if (mat && (bm0 & 127) >= vl[bm0 >> 7]) return;   // masked K/V tiles

    __shared__ _Float16 As[64][40];
    __shared__ _Float16 Ws[64][40];
    const int tid = threadIdx.x, wave = tid >> 6, lane = tid & 63;
    const int srow = tid >> 2, sseg = tid & 3;
    const int fr = lane & 15, fg = (lane >> 4) * 8;

    v4f acc[4] = {};
    for (int k0 = 0; k0 < DM; k0 += 32) {
        const float4* ap = (const float4*)(A + (size_t)(bm0 + srow) * DM + k0 + sseg * 8);
        const float4 a0 = ap[0], a1 = ap[1];
        const float4* wp = (const float4*)(W + (size_t)(bn0 + srow) * DM + k0 + sseg * 8);
        const float4 w0 = wp[0], w1 = wp[1];
        __syncthreads();
        *(v8h*)&As[srow][sseg * 8] = cvt8(a0, a1);
        *(v8h*)&Ws[srow][sseg * 8] = cvt8(w0, w1);
        __syncthreads();
        const v8h af = *(const v8h*)&As[wave * 16 + fr][fg];
        #pragma unroll
        for (int sn = 0; sn < 4; ++sn) {
            const v8h bf = *(const v8h*)&Ws[sn * 16 + fr][fg];
            acc[sn] = __builtin_amdgcn_mfma_f32_16x16x32_f16(af, bf, acc[sn], 0, 0, 0);
        }
    }
    #pragma unroll
    for (int sn = 0; sn < 4; ++sn)
        #pragma unroll
        for (int rg = 0; rg < 4; ++rg) {
            const int row = bm0 + wave * 16 + (lane >> 4) * 4 + rg;
            const int col = bn0 + sn * 16 + fr;
            const float val = acc[sn][rg];
            if (mat == 0)      Qh[(size_t)row * DM + col] = (_Float16)val;
            else if (mat == 1) Kh[(size_t)row * DM + col] = (_Float16)val;
            else               V[(size_t)row * DM + col] = val;
        }
}

// ---------------- Stage 2: qf/kf = head-gathered Q/K @ Wa^T via MFMA --------
__global__ __launch_bounds__(256) void feat_mfma(
    const _Float16* __restrict__ Qh, const _Float16* __restrict__ Kh,
    const float* __restrict__ Wqa, const float* __restrict__ Wka,
    const int* __restrict__ vl, float* __restrict__ qf, float* __restrict__ kf)
{
    const int mat = blockIdx.z;
    const int bm0 = blockIdx.y * 64, bn0 = blockIdx.x * 64;
    if (mat && (bm0 & 127) >= vl[bm0 >> 10]) return;
    const _Float16* Asrc = mat ? Kh : Qh;
    const float* W = mat ? Wka : Wqa;
    float* C = mat ? kf : qf;

    __shared__ _Float16 As[64][40];
    __shared__ _Float16 Ws[64][40];
    const int tid = threadIdx.x, wave = tid >> 6, lane = tid & 63;
    const int srow = tid >> 2, sseg = tid & 3;
    const int fr = lane & 15, fg = (lane >> 4) * 8;

    const int r = bm0 + srow;
    const int b = r >> 10, h = (r >> 7) & 7, l = r & 127;
    const _Float16* arow = Asrc + (size_t)(b * LQL + l) * DM + h * DH;

    v4f acc[4] = {};
    #pragma unroll
    for (int k0 = 0; k0 < DH; k0 += 32) {
        const v8h ha = *(const v8h*)(arow + k0 + sseg * 8);
        const float4* wp = (const float4*)(W + (size_t)(bn0 + srow) * DH + k0 + sseg * 8);
        const float4 w0 = wp[0], w1 = wp[1];
        __syncthreads();
        *(v8h*)&As[srow][sseg * 8] = ha;
        *(v8h*)&Ws[srow][sseg * 8] = cvt8(w0, w1);
        __syncthreads();
        const v8h af = *(const v8h*)&As[wave * 16 + fr][fg];
        #pragma unroll
        for (int sn = 0; sn < 4; ++sn) {
            const v8h bf = *(const v8h*)&Ws[sn * 16 + fr][fg];
            acc[sn] = __builtin_amdgcn_mfma_f32_16x16x32_f16(af, bf, acc[sn], 0, 0, 0);
        }
    }
    #pragma unroll
    for (int sn = 0; sn < 4; ++sn)
        #pragma unroll
        for (int rg = 0; rg < 4; ++rg) {
            const int row = bm0 + wave * 16 + (lane >> 4) * 4 + rg;
            const int col = bn0 + sn * 16 + fr;
            C[(size_t)row * DM + col] = acc[sn][rg];
        }
}

// ---------------- Stage 3: fused score + masked softmax + PV (fp32) ---------
// 512 blocks (b,h,qtile of 4), 512 thr = 8 waves. Wave w owns k in
// [w*16, w*16+16): lane = (k&15) | (fq<<4). Skip granularity 16 k, spread
// across SIMDs. 2 blocks/CU -> 4 waves/SIMD for trans-latency hiding.
__global__ __launch_bounds__(512, 2) void attn_kernel(
    const float* __restrict__ qf, const float* __restrict__ kf,
    const float* __restrict__ V, const float* __restrict__ wv_a,
    const int* __restrict__ vl, _Float16* __restrict__ interh)
{
    __shared__ float s_qf2[QPB][DM];       // 8 KB
    __shared__ float s_wv2[DM];            // 2 KB
    __shared__ float s_part[4][QPB][132];  // stride 132: conflict-free writes
    __shared__ float s_attn[QPB][LKL];
    __shared__ float s_pv[2][QPB][DH];

    const float C2 = 2.8853900818f;        // 2*log2(e)
    const float LOG2E = 1.4426950409f;

    const int bid = blockIdx.x;
    const int b  = bid >> 8;
    const int h  = (bid >> 5) & 7;
    const int qt = bid & 31;
    const int qbase = qt * QPB;
    const int bh = b * NHEADS + h;
    const int t = threadIdx.x;
    const int Lv = vl[b];

    {   // stage qf (pre-scaled by 2log2e) and wv (pre-scaled by -2)
        const int r = t >> 7, cc = (t & 127) * 4;
        const float4 v = *(const float4*)(qf + ((size_t)(bh * LQL + qbase + r)) * DM + cc);
        s_qf2[r][cc+0] = v.x * C2; s_qf2[r][cc+1] = v.y * C2;
        s_qf2[r][cc+2] = v.z * C2; s_qf2[r][cc+3] = v.w * C2;
        s_wv2[t] = wv_a[t] * -2.0f;
    }
    __syncthreads();

    const int w = t >> 6, lane = t & 63;
    const int k  = w * 16 + (lane & 15);   // wave covers 16 consecutive k
    const int fq = lane >> 4;              // 4 f-quarters within the wave
    float acc[QPB] = {};
    if (k < Lv) {
        const float* kp = kf + ((size_t)(bh * LKL + k)) * DM + fq * 128;
        float4 kA = *(const float4*)kp;
        float4 kB = *(const float4*)(kp + 4);
        #pragma unroll 1
        for (int it = 0; it < 16; ++it) {
            float4 nA, nB;
            if (it < 15) { nA = *(const float4*)(kp + 8); nB = *(const float4*)(kp + 12); }
            else         { nA = kA; nB = kB; }
            const int f0 = fq * 128 + it * 8;
            const float4 w0 = *(const float4*)&s_wv2[f0];
            const float4 w1 = *(const float4*)&s_wv2[f0 + 4];
            #pragma unroll
            for (int q = 0; q < QPB; ++q) {
                const float4 q0 = *(const float4*)&s_qf2[q][f0];
                const float4 q1 = *(const float4*)&s_qf2[q][f0 + 4];
                float a = acc[q];
                a = fmaf(w0.x, frcp(fexp2(fmaf(kA.x, C2, q0.x)) + 1.f), a);
                a = fmaf(w0.y, frcp(fexp2(fmaf(kA.y, C2, q0.y)) + 1.f), a);
                a = fmaf(w0.z, frcp(fexp2(fmaf(kA.z, C2, q0.z)) + 1.f), a);
                a = fmaf(w0.w, frcp(fexp2(fmaf(kA.w, C2, q0.w)) + 1.f), a);
                a = fmaf(w1.x, frcp(fexp2(fmaf(kB.x, C2, q1.x)) + 1.f), a);
                a = fmaf(w1.y, frcp(fexp2(fmaf(kB.y, C2, q1.y)) + 1.f), a);
                a = fmaf(w1.z, frcp(fexp2(fmaf(kB.z, C2, q1.z)) + 1.f), a);
                a = fmaf(w1.w, frcp(fexp2(fmaf(kB.w, C2, q1.w)) + 1.f), a);
                acc[q] = a;
            }
            kA = nA; kB = nB; kp += 8;
        }
    }
    #pragma unroll
    for (int q = 0; q < QPB; ++q) s_part[fq][q][k] = acc[q];
    __syncthreads();

    if (t < 64 * QPB) {   // masked softmax: wave = q-row; lane covers k, k+64
        const int q = t >> 6, ln = t & 63;
        float v0 = -3.0e38f, v1 = -3.0e38f;
        if (ln < Lv)
            v0 = s_part[0][q][ln] + s_part[1][q][ln]
               + s_part[2][q][ln] + s_part[3][q][ln];
        if (ln + 64 < Lv)
            v1 = s_part[0][q][ln+64] + s_part[1][q][ln+64]
               + s_part[2][q][ln+64] + s_part[3][q][ln+64];
        float m = fmaxf(v0, v1);
        #pragma unroll
        for (int off = 32; off; off >>= 1) m = fmaxf(m, __shfl_xor(m, off, 64));
        const float e0 = fexp2((v0 - m) * LOG2E);
        const float e1 = fexp2((v1 - m) * LOG2E);
        float s = e0 + e1;
        #pragma unroll
        for (int off = 32; off; off >>= 1) s += __shfl_xor(s, off, 64);
        const float inv = frcp(s);
        s_attn[q][ln]      = e0 * inv;
        s_attn[q][ln + 64] = e1 * inv;
    }
    __syncthreads();

    {   // PV: thread (kh = t>>8, q = (t>>6)&3, d = t&63); only k < Lv
        const int d = t & 63, q = (t >> 6) & 3, kh = t >> 8;
        const float* vb = V + ((size_t)(b * LKL + kh * 64)) * DM + h * DH + d;
        int kmax = Lv - kh * 64;
        kmax = kmax < 0 ? 0 : (kmax > 64 ? 64 : kmax);
        float a0 = 0.f, a1 = 0.f, a2 = 0.f, a3 = 0.f;
        int kk = 0;
        for (; kk + 4 <= kmax; kk += 4) {
            a0 += s_attn[q][kh*64 + kk+0] * vb[(size_t)(kk+0) * DM];
            a1 += s_attn[q][kh*64 + kk+1] * vb[(size_t)(kk+1) * DM];
            a2 += s_attn[q][kh*64 + kk+2] * vb[(size_t)(kk+2) * DM];
            a3 += s_attn[q][kh*64 + kk+3] * vb[(size_t)(kk+3) * DM];
        }
        for (; kk < kmax; ++kk) a0 += s_attn[q][kh*64 + kk] * vb[(size_t)kk * DM];
        s_pv[kh][q][d] = (a0 + a1) + (a2 + a3);
    }
    __syncthreads();
    if (t < 64 * QPB) {
        const int q = t >> 6, d = t & 63;
        interh[((size_t)(b * LQL + qbase + q)) * DM + h * DH + d] =
            (_Float16)(s_pv[0][q][d] + s_pv[1][q][d]);
    }
}

// ---------------- Stage 4: out = inter @ Wo^T via MFMA (fp32 out) -----------
__global__ __launch_bounds__(256) void out_mfma(
    const _Float16* __restrict__ interh, const float* __restrict__ Wo,
    float* __restrict__ out)
{
    const int bm0 = blockIdx.y * 64, bn0 = blockIdx.x * 64;
    __shared__ _Float16 As[64][40];
    __shared__ _Float16 Ws[64][40];
    const int tid = threadIdx.x, wave = tid >> 6, lane = tid & 63;
    const int srow = tid >> 2, sseg = tid & 3;
    const int fr = lane & 15, fg = (lane >> 4) * 8;

    v4f acc[4] = {};
    for (int k0 = 0; k0 < DM; k0 += 32) {
        const v8h ha = *(const v8h*)(interh + (size_t)(bm0 + srow) * DM + k0 + sseg * 8);
        const float4* wp = (const float4*)(Wo + (size_t)(bn0 + srow) * DM + k0 + sseg * 8);
        const float4 w0 = wp[0], w1 = wp[1];
        __syncthreads();
        *(v8h*)&As[srow][sseg * 8] = ha;
        *(v8h*)&Ws[srow][sseg * 8] = cvt8(w0, w1);
        __syncthreads();
        const v8h af = *(const v8h*)&As[wave * 16 + fr][fg];
        #pragma unroll
        for (int sn = 0; sn < 4; ++sn) {
            const v8h bf = *(const v8h*)&Ws[sn * 16 + fr][fg];
            acc[sn] = __builtin_amdgcn_mfma_f32_16x16x32_f16(af, bf, acc[sn], 0, 0, 0);
        }
    }
    #pragma unroll
    for (int sn = 0; sn < 4; ++sn)
        #pragma unroll
        for (int rg = 0; rg < 4; ++rg) {
            const int row = bm0 + wave * 16 + (lane >> 4) * 4 + rg;
            const int col = bn0 + sn * 16 + fr;
            out[(size_t)row * DM + col] = acc[sn][rg];
        }
}

extern "C" void kernel_launch(void* const* d_in, const int* in_sizes, int n_in,
                              void* d_out, int out_size, void* d_ws, size_t ws_size,
                              hipStream_t stream)
{
    const float* xq   = (const float*)d_in[0];
    const float* xk   = (const float*)d_in[1];
    const float* xv   = (const float*)d_in[2];
    const int*   vl   = (const int*)d_in[3];
    const float* Wq   = (const float*)d_in[4];
    const float* Wk   = (const float*)d_in[5];
    const float* Wv   = (const float*)d_in[6];
    const float* Wo   = (const float*)d_in[7];
    const float* Wqa  = (const float*)d_in[8];
    const float* Wka  = (const float*)d_in[9];
    const float* wv_a = (const float*)d_in[10];
    float* out = (float*)d_out;

    // ws carve (bytes): Qh 256K | Kh 256K | V 512K | qf 4M | kf 4M | interh 256K
    char* base = (char*)d_ws;
    _Float16* Qh     = (_Float16*)(base);
    _Float16* Kh     = (_Float16*)(base + 262144);
    float*    V      = (float*)   (base + 524288);
    float*    qf     = (float*)   (base + 1048576);
    float*    kf     = (float*)   (base + 5242880);
    _Float16* interh = (_Float16*)(base + 9437184);

    qkv_mfma<<<dim3(8, 4, 3), dim3(256), 0, stream>>>(
        xq, xk, xv, Wq, Wk, Wv, vl, Qh, Kh, V);
    feat_mfma<<<dim3(8, 32, 2), dim3(256), 0, stream>>>(
        Qh, Kh, Wqa, Wka, vl, qf, kf);
    attn_kernel<<<dim3(512), dim3(512), 0, stream>>>(
        qf, kf, V, wv_a, vl, interh);
    out_mfma<<<dim3(8, 4), dim3(256), 0, stream>>>(interh, Wo, out);
}